// Round 1
// baseline (577.652 us; speedup 1.0000x reference)
//
#include <hip/hip_runtime.h>

// Problem constants (B=2, C=4, D=64, H=256, W=256) — all spatial dims pow2.
#define WW 256
#define HH 256
#define DD 64
#define BB 2
#define CS (DD * HH * WW)        // 4194304 = channel stride (and per-batch spatial size)
#define NSPATIAL (BB * CS)       // 8388608 spatial voxels
#define NTOT (BB * 3 * CS)       // 25165824 loss terms (3 foreground classes)

// softmax at one voxel: returns probs for classes 1..3 (class 0 dropped).
// lidx points at the class-0 element; channels are CS apart.
__device__ __forceinline__ void softmax3(const float* __restrict__ L, int lidx,
                                         float& p1, float& p2, float& p3) {
    float x0 = L[lidx];
    float x1 = L[lidx + CS];
    float x2 = L[lidx + 2 * CS];
    float x3 = L[lidx + 3 * CS];
    float m  = fmaxf(fmaxf(x0, x1), fmaxf(x2, x3));
    float e0 = __expf(x0 - m);
    float e1 = __expf(x1 - m);
    float e2 = __expf(x2 - m);
    float e3 = __expf(x3 - m);
    float r  = __builtin_amdgcn_rcpf(e0 + e1 + e2 + e3);
    p1 = e1 * r;
    p2 = e2 * r;
    p3 = e3 * r;
}

__global__ __launch_bounds__(256) void boundary_loss_kernel(
        const float* __restrict__ logits,
        const int*   __restrict__ targets,
        float*       __restrict__ out) {
    const int s = blockIdx.x * 256 + threadIdx.x;   // grid sized exactly to NSPATIAL
    const int w = s & (WW - 1);
    const int h = (s >> 8) & (HH - 1);
    const int d = (s >> 16) & (DD - 1);
    const int b = s >> 22;
    const int sp = s & (CS - 1);                    // spatial offset within batch
    const int lidx = (b << 2) * CS + sp;            // logits base (class 0)
    const int tidx = s;                             // targets index (same ordering)

    // center, coefficient -6
    float p1, p2, p3;
    softmax3(logits, lidx, p1, p2, p3);
    float lp1 = -6.f * p1, lp2 = -6.f * p2, lp3 = -6.f * p3;
    int t = targets[tidx];
    float lt1 = -6.f * (t == 1), lt2 = -6.f * (t == 2), lt3 = -6.f * (t == 3);

    // 6 neighbors, coefficient +1, zero padding outside the volume
#define POINT(off)                                                   \
    {                                                                \
        softmax3(logits, lidx + (off), p1, p2, p3);                  \
        lp1 += p1; lp2 += p2; lp3 += p3;                             \
        int tt = targets[tidx + (off)];                              \
        lt1 += (tt == 1); lt2 += (tt == 2); lt3 += (tt == 3);        \
    }
    if (w > 0)        POINT(-1);
    if (w < WW - 1)   POINT(1);
    if (h > 0)        POINT(-WW);
    if (h < HH - 1)   POINT(WW);
    if (d > 0)        POINT(-(HH * WW));
    if (d < DD - 1)   POINT(HH * WW);
#undef POINT

    float d1 = fabsf(lp1) - fabsf(lt1);
    float d2 = fabsf(lp2) - fabsf(lt2);
    float d3 = fabsf(lp3) - fabsf(lt3);
    float acc = d1 * d1 + d2 * d2 + d3 * d3;

    // wave-64 shuffle reduction
    for (int o = 32; o > 0; o >>= 1) acc += __shfl_down(acc, o, 64);

    __shared__ float ws[4];
    const int lane = threadIdx.x & 63;
    const int wid  = threadIdx.x >> 6;
    if (lane == 0) ws[wid] = acc;
    __syncthreads();
    if (threadIdx.x == 0) {
        float bsum = ws[0] + ws[1] + ws[2] + ws[3];
        // fold the global mean (1/NTOT) into the per-block contribution
        atomicAdd(out, bsum * (1.0f / (float)NTOT));
    }
}

extern "C" void kernel_launch(void* const* d_in, const int* in_sizes, int n_in,
                              void* d_out, int out_size, void* d_ws, size_t ws_size,
                              hipStream_t stream) {
    const float* logits  = (const float*)d_in[0];
    const int*   targets = (const int*)d_in[1];
    float*       out     = (float*)d_out;

    // d_out is poisoned 0xAA before every timed launch — zero it on-stream.
    hipMemsetAsync(out, 0, sizeof(float), stream);

    boundary_loss_kernel<<<NSPATIAL / 256, 256, 0, stream>>>(logits, targets, out);
}

// Round 2
// 237.526 us; speedup vs baseline: 2.4320x; 2.4320x over previous
//
#include <hip/hip_runtime.h>

// Problem: B=2, C=4, D=64, H=256, W=256; 7-point |Laplacian| MSE between
// softmax probs (classes 1..3) and one-hot targets, mean over all terms.
#define WW 256
#define HH 256
#define DD 64
#define HWs (HH * WW)            // 65536
#define CS (DD * HWs)            // 4194304 = channel stride = per-batch spatial
#define NTOT (2 * 3 * CS)        // 25165824 loss terms

// LDS plane-march tiling: block covers TW x TH (w x h) incl. 1-voxel halo.
#define TW 32
#define TH 8
#define IW 30                    // interior w  (TW-2)
#define IH 6                     // interior h  (TH-2)
#define IDD 32                   // interior d per block (d-split x2)
#define WT 9                     // ceil(256/30)
#define HT 43                    // ceil(256/6)
#define NBLOCKS (WT * HT * 2 * 2)  // x2 d-tiles x2 batches = 1548

struct PV { float p1, p2, p3; int t; };

// softmax probs (classes 1..3) + target at plane d; zeros / t=-1 outside volume.
__device__ __forceinline__ PV load_plane(const float* __restrict__ L,
                                         const int* __restrict__ T,
                                         long lbase, long tbase, int d, bool valid) {
    PV r; r.p1 = 0.f; r.p2 = 0.f; r.p3 = 0.f; r.t = -1;
    if (valid && (unsigned)d < DD) {
        const long off = lbase + (long)d * HWs;
        float x0 = L[off];
        float x1 = L[off + CS];
        float x2 = L[off + 2 * CS];
        float x3 = L[off + 3 * CS];
        float m  = fmaxf(fmaxf(x0, x1), fmaxf(x2, x3));
        float e0 = __expf(x0 - m);
        float e1 = __expf(x1 - m);
        float e2 = __expf(x2 - m);
        float e3 = __expf(x3 - m);
        float rs = __builtin_amdgcn_rcpf(e0 + e1 + e2 + e3);
        r.p1 = e1 * rs; r.p2 = e2 * rs; r.p3 = e3 * rs;
        r.t  = T[tbase + (long)d * HWs];
    }
    return r;
}

__global__ __launch_bounds__(256) void boundary_loss_kernel(
        const float* __restrict__ logits,
        const int*   __restrict__ targets,
        float*       __restrict__ out) {
    const int tw = threadIdx.x & (TW - 1);
    const int th = threadIdx.x >> 5;
    int bidx = blockIdx.x;
    const int wt = bidx % WT; bidx /= WT;
    const int ht = bidx % HT; bidx /= HT;
    const int dt = bidx & 1;  bidx >>= 1;
    const int b  = bidx;                       // 0..1

    const int w = wt * IW + tw - 1;
    const int h = ht * IH + th - 1;
    const bool valid    = ((unsigned)w < WW) && ((unsigned)h < HH);
    const bool interior = ((unsigned)(tw - 1) < IW) && ((unsigned)(th - 1) < IH)
                          && (w < WW) && (h < HH);

    const int  hw    = valid ? (h * WW + w) : 0;     // clamp OOB to safe addr
    const long tbase = (long)b * CS + hw;
    const long lbase = (long)b * 4 * CS + hw;
    const int  d0    = dt * IDD;

    __shared__ float4 plane[TH][TW];   // (p1,p2,p3, bitcast t) per (h,w)

    PV prev = load_plane(logits, targets, lbase, tbase, d0 - 1, valid);
    PV cur  = load_plane(logits, targets, lbase, tbase, d0,     valid);

    float acc = 0.f;
    for (int d = d0; d < d0 + IDD; ++d) {
        // global loads for plane d+1 issue here; latency overlaps LDS phase
        PV nxt = load_plane(logits, targets, lbase, tbase, d + 1, valid);

        __syncthreads();   // previous iteration's readers done
        plane[th][tw] = make_float4(cur.p1, cur.p2, cur.p3, __int_as_float(cur.t));
        __syncthreads();

        if (interior) {
            float4 nL = plane[th][tw - 1];
            float4 nR = plane[th][tw + 1];
            float4 nU = plane[th - 1][tw];
            float4 nD = plane[th + 1][tw];
            float l1 = prev.p1 + nxt.p1 - 6.f * cur.p1 + nL.x + nR.x + nU.x + nD.x;
            float l2 = prev.p2 + nxt.p2 - 6.f * cur.p2 + nL.y + nR.y + nU.y + nD.y;
            float l3 = prev.p3 + nxt.p3 - 6.f * cur.p3 + nL.z + nR.z + nU.z + nD.z;
            const int tL = __float_as_int(nL.w), tR = __float_as_int(nR.w);
            const int tU = __float_as_int(nU.w), tB = __float_as_int(nD.w);
            float m1 = (float)((prev.t == 1) + (nxt.t == 1) + (tL == 1) + (tR == 1)
                             + (tU == 1) + (tB == 1) - 6 * (cur.t == 1));
            float m2 = (float)((prev.t == 2) + (nxt.t == 2) + (tL == 2) + (tR == 2)
                             + (tU == 2) + (tB == 2) - 6 * (cur.t == 2));
            float m3 = (float)((prev.t == 3) + (nxt.t == 3) + (tL == 3) + (tR == 3)
                             + (tU == 3) + (tB == 3) - 6 * (cur.t == 3));
            float d1 = fabsf(l1) - fabsf(m1);
            float d2 = fabsf(l2) - fabsf(m2);
            float d3 = fabsf(l3) - fabsf(m3);
            acc += d1 * d1 + d2 * d2 + d3 * d3;
        }
        prev = cur; cur = nxt;
    }

    // wave-64 shuffle reduction, then block sum, one atomic per block
    for (int o = 32; o > 0; o >>= 1) acc += __shfl_down(acc, o, 64);
    __shared__ float wsum[4];
    const int lane = threadIdx.x & 63;
    const int wid  = threadIdx.x >> 6;
    if (lane == 0) wsum[wid] = acc;
    __syncthreads();
    if (threadIdx.x == 0) {
        atomicAdd(out, (wsum[0] + wsum[1] + wsum[2] + wsum[3]) * (1.0f / (float)NTOT));
    }
}

extern "C" void kernel_launch(void* const* d_in, const int* in_sizes, int n_in,
                              void* d_out, int out_size, void* d_ws, size_t ws_size,
                              hipStream_t stream) {
    const float* logits  = (const float*)d_in[0];
    const int*   targets = (const int*)d_in[1];
    float*       out     = (float*)d_out;

    hipMemsetAsync(out, 0, sizeof(float), stream);   // d_out is poisoned 0xAA
    boundary_loss_kernel<<<NBLOCKS, 256, 0, stream>>>(logits, targets, out);
}

// Round 3
// 228.861 us; speedup vs baseline: 2.5240x; 1.0379x over previous
//
#include <hip/hip_runtime.h>

// B=2, C=4, D=64, H=256, W=256. 7-point |Laplacian| MSE between softmax
// probs (classes 1..3) and one-hot targets, mean over all 3*B*D*H*W terms.
//
// Structure: plane-march in d with accumulator form. Each thread owns a quad
// of 4 consecutive w voxels (float4/int4 loads). Block = 32 quad-threads (w)
// x 10 rows (8 interior + 2 halo). Tiles: 2(w) x 32(h) x 8(d) x 2(b) = 1024
// blocks == 4 per CU exactly. LDS keeps one SoA plane (p1,p2,p3,packed-oh);
// w-halo columns (2 per tile) are computed by edge threads.

#define HWs 65536            // H*W  (1<<16)
#define CS  (1 << 22)        // per-batch spatial size
#define NTOT_INV (1.0f / 25165824.0f)
#define IH   8               // interior rows per block
#define IDD  8               // interior planes per block
#define LDW  132             // LDS row stride; cols 0..129 = tile+pad, 130/131 = w-halo
#define BIAS3 ((8 << 20) | (8 << 10) | 8)

__device__ __forceinline__ void smax1(float x0, float x1, float x2, float x3,
                                      float vm, float& p1, float& p2, float& p3) {
    float m  = fmaxf(fmaxf(x0, x1), fmaxf(x2, x3));
    float e0 = __expf(x0 - m);
    float e1 = __expf(x1 - m);
    float e2 = __expf(x2 - m);
    float e3 = __expf(x3 - m);
    float r  = vm * __builtin_amdgcn_rcpf(e0 + e1 + e2 + e3);
    p1 = e1 * r; p2 = e2 * r; p3 = e3 * r;
}

// packed one-hot: class k in {1,2,3} -> 1 << ((k-1)*10); 0/masked -> 0
__device__ __forceinline__ int ohenc(int t, int msk) {
    int nz = (t > 0) ? 1 : 0;
    int v  = nz << (((t - 1) & 3) * 10);
    return v & msk;
}

__global__ __launch_bounds__(320, 4) void boundary_loss_kernel(
        const float* __restrict__ L,
        const int*   __restrict__ T,
        float*       __restrict__ out) {
    const int tid = threadIdx.x;
    const int tw  = tid & 31;
    const int th  = tid >> 5;                 // 0..9
    int bi = blockIdx.x;
    const int wt = bi & 1;
    const int ht = (bi >> 1) & 31;
    const int dt = (bi >> 6) & 7;
    const int b  = bi >> 9;

    const int   w0   = wt << 7;
    const int   h    = (ht << 3) + th - 1;
    const int   hcl  = min(max(h, 0), 255);
    const bool  hval = (h == hcl);
    const float vmh  = hval ? 1.0f : 0.0f;
    const int   ohm  = hval ? ~0 : 0;
    const bool  inter = (th >= 1) && (th <= IH);

    const int sp    = (hcl << 8) + w0 + (tw << 2);
    const int tBase = b * CS + sp;
    const int lBase = (b << 2) * CS + sp;

    // w-halo column duty (2 columns per tile, rows 1..8 only)
    const bool  edge   = inter && (tw == 0 || tw == 31);
    const int   whl    = (tw == 0) ? (w0 - 1) : (w0 + 128);
    const int   whcl   = min(max(whl, 0), 255);
    const bool  hvalid = edge && ((unsigned)whl < 256u);
    const float vmhh   = hvalid ? 1.0f : 0.0f;
    const int   ohmh   = hvalid ? ~0 : 0;
    const int   sph    = (hcl << 8) + whcl;
    const int   tBaseH = b * CS + sph;
    const int   lBaseH = (b << 2) * CS + sph;
    const int   hcol   = (tw == 0) ? 130 : 131;

    const int d0 = dt << 3;

    __shared__ float P1[10][LDW], P2[10][LDW], P3[10][LDW];
    __shared__ int   OHS[10][LDW];

    float4 c1, c2, c3; int4 coh;            // current plane probs / packed t
    float4 a1, a2, a3; int4 aT;             // accumulator for current plane's Laplacian
    float  hcp1 = 0.f, hcp2 = 0.f, hcp3 = 0.f; int hcoh = 0;   // halo col, cur plane
    float  accv = 0.f;

    // ---- preload plane d0-1 into accumulator ----
    if (dt > 0) {
        const int off = (d0 - 1) << 16;
        float4 q0 = *(const float4*)(L + lBase + off);
        float4 q1 = *(const float4*)(L + lBase + off + CS);
        float4 q2 = *(const float4*)(L + lBase + off + 2 * CS);
        float4 q3 = *(const float4*)(L + lBase + off + 3 * CS);
        int4   qt = *(const int4*)(T + tBase + off);
        smax1(q0.x, q1.x, q2.x, q3.x, vmh, a1.x, a2.x, a3.x);
        smax1(q0.y, q1.y, q2.y, q3.y, vmh, a1.y, a2.y, a3.y);
        smax1(q0.z, q1.z, q2.z, q3.z, vmh, a1.z, a2.z, a3.z);
        smax1(q0.w, q1.w, q2.w, q3.w, vmh, a1.w, a2.w, a3.w);
        aT.x = ohenc(qt.x, ohm); aT.y = ohenc(qt.y, ohm);
        aT.z = ohenc(qt.z, ohm); aT.w = ohenc(qt.w, ohm);
    } else {
        a1 = a2 = a3 = make_float4(0.f, 0.f, 0.f, 0.f);
        aT = make_int4(0, 0, 0, 0);
    }
    aT.x += BIAS3; aT.y += BIAS3; aT.z += BIAS3; aT.w += BIAS3;

    // ---- preload plane d0 into cur ----
    {
        const int off = d0 << 16;
        float4 q0 = *(const float4*)(L + lBase + off);
        float4 q1 = *(const float4*)(L + lBase + off + CS);
        float4 q2 = *(const float4*)(L + lBase + off + 2 * CS);
        float4 q3 = *(const float4*)(L + lBase + off + 3 * CS);
        int4   qt = *(const int4*)(T + tBase + off);
        smax1(q0.x, q1.x, q2.x, q3.x, vmh, c1.x, c2.x, c3.x);
        smax1(q0.y, q1.y, q2.y, q3.y, vmh, c1.y, c2.y, c3.y);
        smax1(q0.z, q1.z, q2.z, q3.z, vmh, c1.z, c2.z, c3.z);
        smax1(q0.w, q1.w, q2.w, q3.w, vmh, c1.w, c2.w, c3.w);
        coh.x = ohenc(qt.x, ohm); coh.y = ohenc(qt.y, ohm);
        coh.z = ohenc(qt.z, ohm); coh.w = ohenc(qt.w, ohm);
        if (edge) {
            float x0 = L[lBaseH + off];
            float x1 = L[lBaseH + off + CS];
            float x2 = L[lBaseH + off + 2 * CS];
            float x3 = L[lBaseH + off + 3 * CS];
            int   t  = T[tBaseH + off];
            smax1(x0, x1, x2, x3, vmhh, hcp1, hcp2, hcp3);
            hcoh = ohenc(t, ohmh);
        }
    }

    for (int i = 0; i < IDD; ++i) {
        const int  dn   = d0 + i + 1;
        const bool dval = (dn < 64);          // block-uniform branch
        float4 q0, q1, q2, q3; int4 qt;
        float hx0 = 0.f, hx1 = 0.f, hx2 = 0.f, hx3 = 0.f; int hqt = 0;
        if (dval) {
            const int off = dn << 16;
            q0 = *(const float4*)(L + lBase + off);
            q1 = *(const float4*)(L + lBase + off + CS);
            q2 = *(const float4*)(L + lBase + off + 2 * CS);
            q3 = *(const float4*)(L + lBase + off + 3 * CS);
            qt = *(const int4*)(T + tBase + off);
            if (edge) {
                hx0 = L[lBaseH + off];
                hx1 = L[lBaseH + off + CS];
                hx2 = L[lBaseH + off + 2 * CS];
                hx3 = L[lBaseH + off + 3 * CS];
                hqt = T[tBaseH + off];
            }
        }

        __syncthreads();
        *(float4*)&P1[th][tw << 2] = c1;
        *(float4*)&P2[th][tw << 2] = c2;
        *(float4*)&P3[th][tw << 2] = c3;
        *(int4*)&OHS[th][tw << 2]  = coh;
        if (edge) {
            P1[th][hcol] = hcp1; P2[th][hcol] = hcp2; P3[th][hcol] = hcp3;
            OHS[th][hcol] = hcoh;
        }
        __syncthreads();

        if (inter) {
            const int c0 = tw << 2;
            const int cL = (tw == 0) ? 130 : c0 - 1;
            const int cR = (tw == 31) ? 131 : c0 + 4;

            float4 u, dw; float lf, rt;
            u = *(float4*)&P1[th - 1][c0]; dw = *(float4*)&P1[th + 1][c0];
            lf = P1[th][cL]; rt = P1[th][cR];
            a1.x += u.x + dw.x + lf   + c1.y - 6.f * c1.x;
            a1.y += u.y + dw.y + c1.x + c1.z - 6.f * c1.y;
            a1.z += u.z + dw.z + c1.y + c1.w - 6.f * c1.z;
            a1.w += u.w + dw.w + c1.z + rt   - 6.f * c1.w;
            u = *(float4*)&P2[th - 1][c0]; dw = *(float4*)&P2[th + 1][c0];
            lf = P2[th][cL]; rt = P2[th][cR];
            a2.x += u.x + dw.x + lf   + c2.y - 6.f * c2.x;
            a2.y += u.y + dw.y + c2.x + c2.z - 6.f * c2.y;
            a2.z += u.z + dw.z + c2.y + c2.w - 6.f * c2.z;
            a2.w += u.w + dw.w + c2.z + rt   - 6.f * c2.w;
            u = *(float4*)&P3[th - 1][c0]; dw = *(float4*)&P3[th + 1][c0];
            lf = P3[th][cL]; rt = P3[th][cR];
            a3.x += u.x + dw.x + lf   + c3.y - 6.f * c3.x;
            a3.y += u.y + dw.y + c3.x + c3.z - 6.f * c3.y;
            a3.z += u.z + dw.z + c3.y + c3.w - 6.f * c3.z;
            a3.w += u.w + dw.w + c3.z + rt   - 6.f * c3.w;

            int4 iu = *(int4*)&OHS[th - 1][c0];
            int4 id = *(int4*)&OHS[th + 1][c0];
            int  il = OHS[th][cL], ir = OHS[th][cR];
            aT.x += iu.x + id.x + il    + coh.y - 6 * coh.x;
            aT.y += iu.y + id.y + coh.x + coh.z - 6 * coh.y;
            aT.z += iu.z + id.z + coh.y + coh.w - 6 * coh.z;
            aT.w += iu.w + id.w + coh.z + ir    - 6 * coh.w;
        }

        // softmax of next plane (loads issued at step start; latency covered)
        float4 n1, n2, n3; int4 noh;
        float hn1 = 0.f, hn2 = 0.f, hn3 = 0.f; int hnoh = 0;
        if (dval) {
            smax1(q0.x, q1.x, q2.x, q3.x, vmh, n1.x, n2.x, n3.x);
            smax1(q0.y, q1.y, q2.y, q3.y, vmh, n1.y, n2.y, n3.y);
            smax1(q0.z, q1.z, q2.z, q3.z, vmh, n1.z, n2.z, n3.z);
            smax1(q0.w, q1.w, q2.w, q3.w, vmh, n1.w, n2.w, n3.w);
            noh.x = ohenc(qt.x, ohm); noh.y = ohenc(qt.y, ohm);
            noh.z = ohenc(qt.z, ohm); noh.w = ohenc(qt.w, ohm);
            if (edge) {
                smax1(hx0, hx1, hx2, hx3, vmhh, hn1, hn2, hn3);
                hnoh = ohenc(hqt, ohmh);
            }
        } else {
            n1 = n2 = n3 = make_float4(0.f, 0.f, 0.f, 0.f);
            noh = make_int4(0, 0, 0, 0);
        }

        if (inter) {
            // retire plane d0+i: lap = acc + next-plane contribution
            int t0 = aT.x + noh.x, t1 = aT.y + noh.y,
                t2 = aT.z + noh.z, t3 = aT.w + noh.w;
            float lp, lt, df;
            lp = fabsf(a1.x + n1.x); lt = fabsf((float)((t0 & 1023) - 8));         df = lp - lt; accv = fmaf(df, df, accv);
            lp = fabsf(a2.x + n2.x); lt = fabsf((float)(((t0 >> 10) & 1023) - 8)); df = lp - lt; accv = fmaf(df, df, accv);
            lp = fabsf(a3.x + n3.x); lt = fabsf((float)(((t0 >> 20) & 1023) - 8)); df = lp - lt; accv = fmaf(df, df, accv);
            lp = fabsf(a1.y + n1.y); lt = fabsf((float)((t1 & 1023) - 8));         df = lp - lt; accv = fmaf(df, df, accv);
            lp = fabsf(a2.y + n2.y); lt = fabsf((float)(((t1 >> 10) & 1023) - 8)); df = lp - lt; accv = fmaf(df, df, accv);
            lp = fabsf(a3.y + n3.y); lt = fabsf((float)(((t1 >> 20) & 1023) - 8)); df = lp - lt; accv = fmaf(df, df, accv);
            lp = fabsf(a1.z + n1.z); lt = fabsf((float)((t2 & 1023) - 8));         df = lp - lt; accv = fmaf(df, df, accv);
            lp = fabsf(a2.z + n2.z); lt = fabsf((float)(((t2 >> 10) & 1023) - 8)); df = lp - lt; accv = fmaf(df, df, accv);
            lp = fabsf(a3.z + n3.z); lt = fabsf((float)(((t2 >> 20) & 1023) - 8)); df = lp - lt; accv = fmaf(df, df, accv);
            lp = fabsf(a1.w + n1.w); lt = fabsf((float)((t3 & 1023) - 8));         df = lp - lt; accv = fmaf(df, df, accv);
            lp = fabsf(a2.w + n2.w); lt = fabsf((float)(((t3 >> 10) & 1023) - 8)); df = lp - lt; accv = fmaf(df, df, accv);
            lp = fabsf(a3.w + n3.w); lt = fabsf((float)(((t3 >> 20) & 1023) - 8)); df = lp - lt; accv = fmaf(df, df, accv);
        }

        // rotate: cur becomes the "+1 from below" seed of plane d+1's accumulator
        a1 = c1; a2 = c2; a3 = c3;
        aT.x = coh.x + BIAS3; aT.y = coh.y + BIAS3;
        aT.z = coh.z + BIAS3; aT.w = coh.w + BIAS3;
        c1 = n1; c2 = n2; c3 = n3; coh = noh;
        hcp1 = hn1; hcp2 = hn2; hcp3 = hn3; hcoh = hnoh;
    }

    // block reduction: wave shuffle -> LDS -> one atomic
    for (int o = 32; o > 0; o >>= 1) accv += __shfl_down(accv, o, 64);
    __shared__ float wsum[5];
    const int lane = tid & 63, wv = tid >> 6;
    if (lane == 0) wsum[wv] = accv;
    __syncthreads();
    if (tid == 0) {
        float s = wsum[0] + wsum[1] + wsum[2] + wsum[3] + wsum[4];
        atomicAdd(out, s * NTOT_INV);
    }
}

extern "C" void kernel_launch(void* const* d_in, const int* in_sizes, int n_in,
                              void* d_out, int out_size, void* d_ws, size_t ws_size,
                              hipStream_t stream) {
    const float* logits  = (const float*)d_in[0];
    const int*   targets = (const int*)d_in[1];
    float*       out     = (float*)d_out;

    hipMemsetAsync(out, 0, sizeof(float), stream);   // d_out is poisoned 0xAA
    boundary_loss_kernel<<<1024, 320, 0, stream>>>(logits, targets, out);
}